// Round 9
// baseline (232.721 us; speedup 1.0000x reference)
//
#include <hip/hip_runtime.h>
#include <hip/hip_bf16.h>

// DCNv2 inception, R9: branch-free tap loop.
// R8 evidence: all pipes <33% busy, Occ at its LDS cap, VGPR only 64/128 ->
// the per-tap `if (oow)` fallback branch fragments the unrolled loop into
// basic-block diamonds; scheduler can't overlap taps. R9: window-masked
// corner weights via cndmask (branchless), per-tap wave flag via __any into
// a bitmask, straight-line main body; flagged taps (expected ~never:
// 4-7 sigma margin vs N(0,1) offsets) replayed in a cold loop that MFMAs
// the exact bf16 delta (window values recomputed bitwise from global).

typedef __attribute__((ext_vector_type(8))) short bf16x8;
typedef __attribute__((ext_vector_type(8))) unsigned short u16x8;
typedef __attribute__((ext_vector_type(4))) float f32x4;
typedef __attribute__((ext_vector_type(2))) float f32x2;

#define WR 16    // window rows
#define WC 30    // window cols
#define WS 68    // window position stride in shorts (34 dwords -> +2 bank rotate)
#define SLS 20   // slab o-stride in floats

__device__ __forceinline__ float b2f(unsigned short u) {
    return __uint_as_float(((unsigned)u) << 16);
}
__device__ __forceinline__ unsigned short f2bf(float f) {
    __hip_bfloat16 h = __float2bfloat16(f);
    return *reinterpret_cast<unsigned short*>(&h);
}
__device__ __forceinline__ f32x2 unpk(unsigned u) {
    f32x2 r;
    r[0] = __uint_as_float(u << 16);
    r[1] = __uint_as_float(u & 0xffff0000u);
    return r;
}

union G { u16x8 v[2]; unsigned u[8]; };   // 16 channels of one corner

__device__ __forceinline__ void lerp16(
    float w00, float w01, float w10, float w11,
    const G& g00, const G& g01, const G& g10, const G& g11, f32x2 s[8]) {
    f32x2 W00 = {w00, w00}, W01 = {w01, w01}, W10 = {w10, w10}, W11 = {w11, w11};
    #pragma unroll
    for (int j = 0; j < 8; ++j) {
        s[j] = W00 * unpk(g00.u[j]) + W01 * unpk(g01.u[j])
             + W10 * unpk(g10.u[j]) + W11 * unpk(g11.u[j]);
    }
}
__device__ __forceinline__ void pack16(const f32x2 s[8], bf16x8& A0, bf16x8& A1) {
    union { bf16x8 v; unsigned short u[8]; } a0, a1;
    #pragma unroll
    for (int j = 0; j < 4; ++j) {
        a0.u[2 * j]     = f2bf(s[j][0]);
        a0.u[2 * j + 1] = f2bf(s[j][1]);
        a1.u[2 * j]     = f2bf(s[4 + j][0]);
        a1.u[2 * j + 1] = f2bf(s[4 + j][1]);
    }
    A0 = a0.v; A1 = a1.v;
}

// Merged prep: blocks [0,256): x[b][c][h][w] f32 -> xTb[b][h][w][c] bf16;
// blocks [256,1584): f[o][c][k] f32 -> wp[k][o][c] bf16 (all 3 filters).
__global__ __launch_bounds__(256) void k_prep(
    const float* __restrict__ x,
    const float* __restrict__ f1, const float* __restrict__ f2, const float* __restrict__ f3,
    unsigned short* __restrict__ xTb,
    unsigned short* __restrict__ wp1, unsigned short* __restrict__ wp2, unsigned short* __restrict__ wp3) {
    __shared__ float tile[64][65];
    int bid = blockIdx.x;
    int tid = threadIdx.x;
    if (bid < 256) {
        int b = bid >> 6, h = bid & 63;
        {
            int w = tid & 63, c4 = tid >> 6;
            const float* xp = x + (((b * 64) * 64 + h) * 64) + w;
            #pragma unroll
            for (int i = 0; i < 16; ++i) {
                int c = c4 * 16 + i;
                tile[c][w] = xp[c * 4096];
            }
        }
        __syncthreads();
        {
            int c = tid & 63, w4 = tid >> 6;
            unsigned short* op = xTb + (((b * 64 + h) * 64) * 64) + c;
            #pragma unroll
            for (int i = 0; i < 16; ++i) {
                int ww = w4 * 16 + i;
                op[ww * 64] = f2bf(tile[c][ww]);
            }
        }
    } else {
        int idx = (bid - 256) * 256 + tid;      // 83*4096 = 339968 total
        const float* f; unsigned short* wp; int K, rel;
        if (idx < 36864)       { f = f1; wp = wp1; K = 9;  rel = idx; }
        else if (idx < 139264) { f = f2; wp = wp2; K = 25; rel = idx - 36864; }
        else                   { f = f3; wp = wp3; K = 49; rel = idx - 139264; }
        int c = rel & 63;
        int o = (rel >> 6) & 63;
        int k = rel >> 12;
        wp[rel] = f2bf(f[(o * 64 + c) * K + k]);
    }
}

// One tap-range of one branch, accumulating 16px x 64o into acc[4].
template<int KW, int PAD, int KS, int KE>
__device__ __forceinline__ void run_range(
    const float* __restrict__ offp, const float* __restrict__ mskp,
    const unsigned short* __restrict__ wp, const unsigned short* __restrict__ win,
    const unsigned short* __restrict__ xb,
    int h, int pw, int ylo, int cxlo, int ch0, int l16, f32x4 acc[4]) {

    constexpr int NT = KE - KS;

    // ---- batch prefetch: all taps' params at once (one HBM latency) ----
    float dys[NT], dxs[NT], mks[NT];
    #pragma unroll
    for (int i = 0; i < NT; ++i) {
        dys[i] = offp[(KS + i) * 8192];
        dxs[i] = offp[(KS + i) * 8192 + 4096];
        mks[i] = mskp[(KS + i) * 4096];
    }

    unsigned oowmask = 0;

    #pragma unroll
    for (int i = 0; i < NT; ++i) {
        const int k = KS + i;
        const int ky = k / KW, kx = k - ky * KW;
        float mk = mks[i];
        float py = (float)(h - PAD + ky) + dys[i];
        float px = (float)(pw - PAD + kx) + dxs[i];
        float y0f = floorf(py), x0f = floorf(px);
        float wy = py - y0f, wx = px - x0f;
        int y0 = (int)y0f, x0 = (int)x0f;
        int y1 = y0 + 1, x1 = x0 + 1;
        float fy0 = ((unsigned)y0 < 64u) ? (1.f - wy) * mk : 0.f;
        float fy1 = ((unsigned)y1 < 64u) ? wy * mk         : 0.f;
        float gx0 = ((unsigned)x0 < 64u) ? (1.f - wx)      : 0.f;
        float gx1 = ((unsigned)x1 < 64u) ? wx              : 0.f;
        float w00 = fy0 * gx0, w01 = fy0 * gx1, w10 = fy1 * gx0, w11 = fy1 * gx1;

        int r0 = y0 - ylo, r1 = r0 + 1;
        int c0 = x0 - cxlo, c1 = c0 + 1;
        bool i00 = ((unsigned)r0 < WR) & ((unsigned)c0 < WC);
        bool i01 = ((unsigned)r0 < WR) & ((unsigned)c1 < WC);
        bool i10 = ((unsigned)r1 < WR) & ((unsigned)c0 < WC);
        bool i11 = ((unsigned)r1 < WR) & ((unsigned)c1 < WC);
        float m00 = i00 ? w00 : 0.f;   // window-masked weights (cndmask)
        float m01 = i01 ? w01 : 0.f;
        float m10 = i10 ? w10 : 0.f;
        float m11 = i11 ? w11 : 0.f;
        bool oow = (m00 != w00) | (m01 != w01) | (m10 != w10) | (m11 != w11);
        oowmask |= ((unsigned)(__any(oow) != 0)) << i;   // branchless s_cselect

        int r0c = min(max(r0, 0), WR - 1), r1c = min(max(r1, 0), WR - 1);
        int c0c = min(max(c0, 0), WC - 1), c1c = min(max(c1, 0), WC - 1);
        int p00 = (r0c * WC + c0c) * WS;
        int p01 = (r0c * WC + c1c) * WS;
        int p10 = (r1c * WC + c0c) * WS;
        int p11 = (r1c * WC + c1c) * WS;

        G g00, g01, g10, g11;
        g00.v[0] = *(const u16x8*)(win + p00 + ch0);
        g01.v[0] = *(const u16x8*)(win + p01 + ch0);
        g10.v[0] = *(const u16x8*)(win + p10 + ch0);
        g11.v[0] = *(const u16x8*)(win + p11 + ch0);
        g00.v[1] = *(const u16x8*)(win + p00 + 32 + ch0);
        g01.v[1] = *(const u16x8*)(win + p01 + 32 + ch0);
        g10.v[1] = *(const u16x8*)(win + p10 + 32 + ch0);
        g11.v[1] = *(const u16x8*)(win + p11 + 32 + ch0);

        f32x2 s[8];
        lerp16(m00, m01, m10, m11, g00, g01, g10, g11, s);
        bf16x8 A0, A1;
        pack16(s, A0, A1);

        const unsigned short* wpk = wp + (k << 12);
        #pragma unroll
        for (int ct = 0; ct < 4; ++ct) {
            const unsigned short* wr = wpk + ((ct * 16 + l16) << 6);
            bf16x8 b0 = *(const bf16x8*)(wr + ch0);
            bf16x8 b1 = *(const bf16x8*)(wr + 32 + ch0);
            acc[ct] = __builtin_amdgcn_mfma_f32_16x16x32_bf16(A0, b0, acc[ct], 0, 0, 0);
            acc[ct] = __builtin_amdgcn_mfma_f32_16x16x32_bf16(A1, b1, acc[ct], 0, 0, 0);
        }
    }

    // ---- cold replay: exact delta for taps with out-of-window valid corner ----
    if (__builtin_expect(oowmask != 0u, 0)) {
        #pragma unroll 1
        for (int i = 0; i < NT; ++i) {
            if (!((oowmask >> i) & 1u)) continue;
            const int k = KS + i;
            int ky = k / KW, kx = k - ky * KW;
            float dy = offp[k * 8192];
            float dx = offp[k * 8192 + 4096];
            float mk = mskp[k * 4096];
            float py = (float)(h - PAD + ky) + dy;
            float px = (float)(pw - PAD + kx) + dx;
            float y0f = floorf(py), x0f = floorf(px);
            float wy = py - y0f, wx = px - x0f;
            int y0 = (int)y0f, x0 = (int)x0f;
            int y1 = y0 + 1, x1 = x0 + 1;
            float fy0 = ((unsigned)y0 < 64u) ? (1.f - wy) * mk : 0.f;
            float fy1 = ((unsigned)y1 < 64u) ? wy * mk         : 0.f;
            float gx0 = ((unsigned)x0 < 64u) ? (1.f - wx)      : 0.f;
            float gx1 = ((unsigned)x1 < 64u) ? wx              : 0.f;
            float w00 = fy0 * gx0, w01 = fy0 * gx1, w10 = fy1 * gx0, w11 = fy1 * gx1;
            int r0 = y0 - ylo, r1 = r0 + 1;
            int c0 = x0 - cxlo, c1 = c0 + 1;
            bool i00 = ((unsigned)r0 < WR) & ((unsigned)c0 < WC);
            bool i01 = ((unsigned)r0 < WR) & ((unsigned)c1 < WC);
            bool i10 = ((unsigned)r1 < WR) & ((unsigned)c0 < WC);
            bool i11 = ((unsigned)r1 < WR) & ((unsigned)c1 < WC);
            float m00 = i00 ? w00 : 0.f;
            float m01 = i01 ? w01 : 0.f;
            float m10 = i10 ? w10 : 0.f;
            float m11 = i11 ? w11 : 0.f;
            int r0c = min(max(r0, 0), WR - 1), r1c = min(max(r1, 0), WR - 1);
            int c0c = min(max(c0, 0), WC - 1), c1c = min(max(c1, 0), WC - 1);
            // main-path values, recomputed bitwise from global (= window contents)
            int ym0 = min(max(ylo + r0c, 0), 63), ym1 = min(max(ylo + r1c, 0), 63);
            int xm0 = min(max(cxlo + c0c, 0), 63), xm1 = min(max(cxlo + c1c, 0), 63);
            // fully-correct values (image clamp, per reference)
            int yf0 = min(max(y0, 0), 63), yf1 = min(max(y1, 0), 63);
            int xf0 = min(max(x0, 0), 63), xf1 = min(max(x1, 0), 63);
            auto ld = [&](int y, int x, G& g) {
                int o = ((y << 6) + x) << 6;
                g.v[0] = *(const u16x8*)(xb + o + ch0);
                g.v[1] = *(const u16x8*)(xb + o + 32 + ch0);
            };
            G a00, a01, a10, a11, f00, f01, f10, f11;
            ld(ym0, xm0, a00); ld(ym0, xm1, a01); ld(ym1, xm0, a10); ld(ym1, xm1, a11);
            ld(yf0, xf0, f00); ld(yf0, xf1, f01); ld(yf1, xf0, f10); ld(yf1, xf1, f11);
            f32x2 sm[8], sf[8], d[8];
            lerp16(m00, m01, m10, m11, a00, a01, a10, a11, sm);
            lerp16(w00, w01, w10, w11, f00, f01, f10, f11, sf);
            #pragma unroll
            for (int j = 0; j < 8; ++j) {
                d[j][0] = b2f(f2bf(sf[j][0])) - b2f(f2bf(sm[j][0]));
                d[j][1] = b2f(f2bf(sf[j][1])) - b2f(f2bf(sm[j][1]));
            }
            bf16x8 A0, A1;
            pack16(d, A0, A1);
            const unsigned short* wpk = wp + (k << 12);
            #pragma unroll
            for (int ct = 0; ct < 4; ++ct) {
                const unsigned short* wr = wpk + ((ct * 16 + l16) << 6);
                bf16x8 b0 = *(const bf16x8*)(wr + ch0);
                bf16x8 b1 = *(const bf16x8*)(wr + 32 + ch0);
                acc[ct] = __builtin_amdgcn_mfma_f32_16x16x32_bf16(A0, b0, acc[ct], 0, 0, 0);
                acc[ct] = __builtin_amdgcn_mfma_f32_16x16x32_bf16(A1, b1, acc[ct], 0, 0, 0);
            }
        }
    }
}

__global__ __launch_bounds__(512, 4) void k_dcn(
    const unsigned short* __restrict__ xTb,
    const float* __restrict__ off1, const float* __restrict__ msk1, const unsigned short* __restrict__ wp1,
    const float* __restrict__ off2, const float* __restrict__ msk2, const unsigned short* __restrict__ wp2,
    const float* __restrict__ off3, const float* __restrict__ msk3, const unsigned short* __restrict__ wp3,
    float* __restrict__ out) {

    __shared__ __align__(16) unsigned char smem[WR * WC * WS * 2];   // 65,280 B
    unsigned short* win = (unsigned short*)smem;
    float* slab = (float*)smem;          // aliased after taps complete (9*1280*4 = 46,080 B)

    int tile = blockIdx.x;               // 0..1023
    int b  = tile >> 8;
    int h  = (tile >> 2) & 63;
    int w0 = (tile & 3) << 4;

    int tid  = threadIdx.x;
    int wv   = tid >> 6;                 // 0..7
    int lane = tid & 63;
    int quad = lane >> 4;
    int l16  = lane & 15;
    int ylo  = h - 7, cxlo = w0 - 7;

    const unsigned short* xb = xTb + ((size_t)b << 18);

    // ---- stage window: 480 positions x 128 B, coalesced, 512 threads ----
    {
        int j = tid & 7;
        for (int p = tid >> 3; p < WR * WC; p += 64) {
            int r = p / WC, cc = p - r * WC;
            int y = min(max(ylo + r, 0), 63);
            int x = min(max(cxlo + cc, 0), 63);
            *(u16x8*)(win + p * WS + j * 8) =
                *(const u16x8*)(xb + (((y << 6) + x) << 6) + j * 8);
        }
    }
    __syncthreads();

    int pw  = w0 + l16;
    int ch0 = quad << 3;
    const float* o1p = off1 + (b * 18) * 4096 + (h << 6) + pw;
    const float* m1p = msk1 + (b * 9)  * 4096 + (h << 6) + pw;
    const float* o2p = off2 + (b * 50) * 4096 + (h << 6) + pw;
    const float* m2p = msk2 + (b * 25) * 4096 + (h << 6) + pw;
    const float* o3p = off3 + (b * 98) * 4096 + (h << 6) + pw;
    const float* m3p = msk3 + (b * 49) * 4096 + (h << 6) + pw;

    f32x4 accA[4], accB[4];
    #pragma unroll
    for (int i = 0; i < 4; ++i) { accA[i] = (f32x4){0,0,0,0}; accB[i] = (f32x4){0,0,0,0}; }
    int slabA, slabB = -1;

    // 8 balanced compile-time chunks over 83 taps: 9/11/11/(3+8)/10/10/10/11
    switch (wv) {
        case 0:
            run_range<3,1,0,9>  (o1p, m1p, wp1, win, xb, h, pw, ylo, cxlo, ch0, l16, accA);
            slabA = 0; break;
        case 1:
            run_range<5,2,0,11> (o2p, m2p, wp2, win, xb, h, pw, ylo, cxlo, ch0, l16, accA);
            slabA = 1; break;
        case 2:
            run_range<5,2,11,22>(o2p, m2p, wp2, win, xb, h, pw, ylo, cxlo, ch0, l16, accA);
            slabA = 2; break;
        case 3:
            run_range<5,2,22,25>(o2p, m2p, wp2, win, xb, h, pw, ylo, cxlo, ch0, l16, accA);
            slabA = 3;
            run_range<7,3,0,8>  (o3p, m3p, wp3, win, xb, h, pw, ylo, cxlo, ch0, l16, accB);
            slabB = 4; break;
        case 4:
            run_range<7,3,8,18> (o3p, m3p, wp3, win, xb, h, pw, ylo, cxlo, ch0, l16, accA);
            slabA = 5; break;
        case 5:
            run_range<7,3,18,28>(o3p, m3p, wp3, win, xb, h, pw, ylo, cxlo, ch0, l16, accA);
            slabA = 6; break;
        case 6:
            run_range<7,3,28,38>(o3p, m3p, wp3, win, xb, h, pw, ylo, cxlo, ch0, l16, accA);
            slabA = 7; break;
        default:
            run_range<7,3,38,49>(o3p, m3p, wp3, win, xb, h, pw, ylo, cxlo, ch0, l16, accA);
            slabA = 8; break;
    }

    __syncthreads();    // all waves done reading window; safe to alias as slab

    #pragma unroll
    for (int ct = 0; ct < 4; ++ct) {
        *(f32x4*)&slab[slabA * 1280 + (ct * 16 + l16) * SLS + quad * 4] = accA[ct];
    }
    if (slabB >= 0) {
        #pragma unroll
        for (int ct = 0; ct < 4; ++ct) {
            *(f32x4*)&slab[slabB * 1280 + (ct * 16 + l16) * SLS + quad * 4] = accB[ct];
        }
    }
    __syncthreads();

    // in-block reduce + store: 768 items = 192 o x 4 groups of 4 px
    // br0 (o<64): slab 0; br1: slabs 1+2+3; br2: slabs 4..8
    for (int it = tid; it < 768; it += 512) {
        int g = it & 3;
        int o = it >> 2;            // 0..191 (concat order br0|br1|br2)
        int oo = o & 63;
        int base = oo * SLS + g * 4;
        f32x4 v;
        if (o < 64) {
            v = *(const f32x4*)&slab[base];
        } else if (o < 128) {
            f32x4 a0 = *(const f32x4*)&slab[1 * 1280 + base];
            f32x4 a1 = *(const f32x4*)&slab[2 * 1280 + base];
            f32x4 a2 = *(const f32x4*)&slab[3 * 1280 + base];
            #pragma unroll
            for (int r = 0; r < 4; ++r) v[r] = a0[r] + (a1[r] + a2[r]);
        } else {
            f32x4 a0 = *(const f32x4*)&slab[4 * 1280 + base];
            f32x4 a1 = *(const f32x4*)&slab[5 * 1280 + base];
            f32x4 a2 = *(const f32x4*)&slab[6 * 1280 + base];
            f32x4 a3 = *(const f32x4*)&slab[7 * 1280 + base];
            f32x4 a4 = *(const f32x4*)&slab[8 * 1280 + base];
            #pragma unroll
            for (int r = 0; r < 4; ++r) v[r] = (a0[r] + a1[r]) + (a2[r] + a3[r]) + a4[r];
        }
        *(f32x4*)&out[(((size_t)b * 192 + o) * 64 + h) * 64 + w0 + g * 4] = v;
    }
}

extern "C" void kernel_launch(void* const* d_in, const int* in_sizes, int n_in,
                              void* d_out, int out_size, void* d_ws, size_t ws_size,
                              hipStream_t stream) {
    const float* x    = (const float*)d_in[0];
    const float* f1   = (const float*)d_in[1];
    const float* off1 = (const float*)d_in[2];
    const float* msk1 = (const float*)d_in[3];
    const float* f2   = (const float*)d_in[4];
    const float* off2 = (const float*)d_in[5];
    const float* msk2 = (const float*)d_in[6];
    const float* f3   = (const float*)d_in[7];
    const float* off3 = (const float*)d_in[8];
    const float* msk3 = (const float*)d_in[9];
    float* out = (float*)d_out;

    // ws: xTb 2MB bf16 | wp1/wp2/wp3 bf16
    unsigned short* xTb = (unsigned short*)d_ws;
    unsigned short* wp1 = xTb + 4 * 64 * 64 * 64;
    unsigned short* wp2 = wp1 + 9 * 4096;
    unsigned short* wp3 = wp2 + 25 * 4096;

    k_prep<<<dim3(1584), dim3(256), 0, stream>>>(x, f1, f2, f3, xTb, wp1, wp2, wp3);
    k_dcn<<<dim3(1024), dim3(512), 0, stream>>>(xTb,
                                                off1, msk1, wp1,
                                                off2, msk2, wp2,
                                                off3, msk3, wp3,
                                                out);
}

// Round 10
// 196.456 us; speedup vs baseline: 1.1846x; 1.1846x over previous
//
#include <hip/hip_runtime.h>
#include <hip/hip_bf16.h>

// DCNv2 inception, R10: waves-per-window attack (R9 reverted: spill storm).
// R8 base (95us, VGPR=64) is LDS-capped at 16 waves/CU; chains unhidden.
// R10: 1024-thr block = 16 waves share ONE 65KB window; each wave does a
// (tap-chunk, channel-half): K=32 MFMA, 4 ds gathers, 4 B loads, lerp8 ->
// per-tap state halves so the kernel can fit <=64 VGPR, enabling
// 2 blocks/CU = 32 waves/CU (100%). __launch_bounds__(1024,8) forces the
// 64-reg cap. 8 single-range chunks (9|12+13|10/10/10/10/9) x 2 halves;
// halves merged by an LDS add phase; in-loop param loads (TLP hides them).

typedef __attribute__((ext_vector_type(8))) short bf16x8;
typedef __attribute__((ext_vector_type(8))) unsigned short u16x8;
typedef __attribute__((ext_vector_type(4))) float f32x4;
typedef __attribute__((ext_vector_type(2))) float f32x2;

#define WR 16    // window rows
#define WC 30    // window cols
#define WS 68    // window position stride in shorts (proven R6-R8 layout)
#define SLS 20   // slab o-stride in floats

__device__ __forceinline__ unsigned short f2bf(float f) {
    __hip_bfloat16 h = __float2bfloat16(f);
    return *reinterpret_cast<unsigned short*>(&h);
}
__device__ __forceinline__ f32x2 unpk(unsigned u) {
    f32x2 r;
    r[0] = __uint_as_float(u << 16);
    r[1] = __uint_as_float(u & 0xffff0000u);
    return r;
}

// Merged prep: blocks [0,256): x[b][c][h][w] f32 -> xTb[b][h][w][c] bf16;
// blocks [256,1584): f[o][c][k] f32 -> wp[k][o][c] bf16 (all 3 filters).
__global__ __launch_bounds__(256) void k_prep(
    const float* __restrict__ x,
    const float* __restrict__ f1, const float* __restrict__ f2, const float* __restrict__ f3,
    unsigned short* __restrict__ xTb,
    unsigned short* __restrict__ wp1, unsigned short* __restrict__ wp2, unsigned short* __restrict__ wp3) {
    __shared__ float tile[64][65];
    int bid = blockIdx.x;
    int tid = threadIdx.x;
    if (bid < 256) {
        int b = bid >> 6, h = bid & 63;
        {
            int w = tid & 63, c4 = tid >> 6;
            const float* xp = x + (((b * 64) * 64 + h) * 64) + w;
            #pragma unroll
            for (int i = 0; i < 16; ++i) {
                int c = c4 * 16 + i;
                tile[c][w] = xp[c * 4096];
            }
        }
        __syncthreads();
        {
            int c = tid & 63, w4 = tid >> 6;
            unsigned short* op = xTb + (((b * 64 + h) * 64) * 64) + c;
            #pragma unroll
            for (int i = 0; i < 16; ++i) {
                int ww = w4 * 16 + i;
                op[ww * 64] = f2bf(tile[c][ww]);
            }
        }
    } else {
        int idx = (bid - 256) * 256 + tid;      // 83*4096 = 339968 total
        const float* f; unsigned short* wp; int K, rel;
        if (idx < 36864)       { f = f1; wp = wp1; K = 9;  rel = idx; }
        else if (idx < 139264) { f = f2; wp = wp2; K = 25; rel = idx - 36864; }
        else                   { f = f3; wp = wp3; K = 49; rel = idx - 139264; }
        int c = rel & 63;
        int o = (rel >> 6) & 63;
        int k = rel >> 12;
        wp[rel] = f2bf(f[(o * 64 + c) * K + k]);
    }
}

// One tap-range, ONE channel-half (ch0 = half*32 + quad*8): K=32 MFMA path.
template<int KW, int PAD, int KS, int KE>
__device__ __forceinline__ void run_range(
    const float* __restrict__ offp, const float* __restrict__ mskp,
    const unsigned short* __restrict__ wp, const unsigned short* __restrict__ win,
    const unsigned short* __restrict__ xb,
    int h, int pw, int ylo, int cxlo, int ch0, int l16, f32x4 acc[4]) {

    #pragma unroll
    for (int k = KS; k < KE; ++k) {
        const int ky = k / KW, kx = k - ky * KW;
        float dy = offp[k * 8192];
        float dx = offp[k * 8192 + 4096];
        float mk = mskp[k * 4096];
        float py = (float)(h - PAD + ky) + dy;
        float px = (float)(pw - PAD + kx) + dx;
        float y0f = floorf(py), x0f = floorf(px);
        float wy = py - y0f, wx = px - x0f;
        int y0 = (int)y0f, x0 = (int)x0f;
        int y1 = y0 + 1, x1 = x0 + 1;
        float fy0 = ((unsigned)y0 < 64u) ? (1.f - wy) * mk : 0.f;
        float fy1 = ((unsigned)y1 < 64u) ? wy * mk         : 0.f;
        float gx0 = ((unsigned)x0 < 64u) ? (1.f - wx)      : 0.f;
        float gx1 = ((unsigned)x1 < 64u) ? wx              : 0.f;
        float w00 = fy0 * gx0, w01 = fy0 * gx1, w10 = fy1 * gx0, w11 = fy1 * gx1;

        int r0 = y0 - ylo, r1 = r0 + 1;
        int c0 = x0 - cxlo, c1 = c0 + 1;
        bool oow = ((w00 != 0.f) & (((unsigned)r0 >= WR) | ((unsigned)c0 >= WC)))
                 | ((w01 != 0.f) & (((unsigned)r0 >= WR) | ((unsigned)c1 >= WC)))
                 | ((w10 != 0.f) & (((unsigned)r1 >= WR) | ((unsigned)c0 >= WC)))
                 | ((w11 != 0.f) & (((unsigned)r1 >= WR) | ((unsigned)c1 >= WC)));
        int r0c = min(max(r0, 0), WR - 1), r1c = min(max(r1, 0), WR - 1);
        int c0c = min(max(c0, 0), WC - 1), c1c = min(max(c1, 0), WC - 1);

        union GU { u16x8 v; unsigned u[4]; } g00, g01, g10, g11;
        g00.v = *(const u16x8*)(win + (r0c * WC + c0c) * WS + ch0);
        g01.v = *(const u16x8*)(win + (r0c * WC + c1c) * WS + ch0);
        g10.v = *(const u16x8*)(win + (r1c * WC + c0c) * WS + ch0);
        g11.v = *(const u16x8*)(win + (r1c * WC + c1c) * WS + ch0);

        if (oow) {   // valid corner outside window: needs |off|>~4sd, rare
            int y0g = min(max(y0, 0), 63), y1g = min(max(y1, 0), 63);
            int x0g = min(max(x0, 0), 63), x1g = min(max(x1, 0), 63);
            g00.v = *(const u16x8*)(xb + (((y0g << 6) + x0g) << 6) + ch0);
            g01.v = *(const u16x8*)(xb + (((y0g << 6) + x1g) << 6) + ch0);
            g10.v = *(const u16x8*)(xb + (((y1g << 6) + x0g) << 6) + ch0);
            g11.v = *(const u16x8*)(xb + (((y1g << 6) + x1g) << 6) + ch0);
        }

        f32x2 W00 = {w00, w00}, W01 = {w01, w01}, W10 = {w10, w10}, W11 = {w11, w11};
        union { bf16x8 v; unsigned short u[8]; } A;
        #pragma unroll
        for (int j = 0; j < 4; ++j) {
            f32x2 s = W00 * unpk(g00.u[j]) + W01 * unpk(g01.u[j])
                    + W10 * unpk(g10.u[j]) + W11 * unpk(g11.u[j]);
            A.u[2 * j]     = f2bf(s[0]);
            A.u[2 * j + 1] = f2bf(s[1]);
        }

        const unsigned short* wpk = wp + (k << 12);
        #pragma unroll
        for (int ct = 0; ct < 4; ++ct) {
            bf16x8 bfr = *(const bf16x8*)(wpk + ((ct * 16 + l16) << 6) + ch0);
            acc[ct] = __builtin_amdgcn_mfma_f32_16x16x32_bf16(A.v, bfr, acc[ct], 0, 0, 0);
        }
    }
}

__global__ __launch_bounds__(1024, 8) void k_dcn(
    const unsigned short* __restrict__ xTb,
    const float* __restrict__ off1, const float* __restrict__ msk1, const unsigned short* __restrict__ wp1,
    const float* __restrict__ off2, const float* __restrict__ msk2, const unsigned short* __restrict__ wp2,
    const float* __restrict__ off3, const float* __restrict__ msk3, const unsigned short* __restrict__ wp3,
    float* __restrict__ out) {

    __shared__ __align__(16) unsigned char smem[WR * WC * WS * 2];   // 65,280 B
    unsigned short* win = (unsigned short*)smem;
    float* slab = (float*)smem;          // aliased after taps (8*1280*4 = 40,960 B)

    int tile = blockIdx.x;               // 0..1023
    int b  = tile >> 8;
    int h  = (tile >> 2) & 63;
    int w0 = (tile & 3) << 4;

    int tid   = threadIdx.x;
    int wv    = tid >> 6;                // 0..15
    int chunk = wv >> 1;                 // 0..7
    int half  = wv & 1;                  // channel half
    int lane  = tid & 63;
    int quad  = lane >> 4;
    int l16   = lane & 15;
    int ylo   = h - 7, cxlo = w0 - 7;

    const unsigned short* xb = xTb + ((size_t)b << 18);

    // ---- stage window: 480 positions x 128 B, coalesced, 1024 threads ----
    {
        int j = tid & 7;
        for (int p = tid >> 3; p < WR * WC; p += 128) {
            int r = p / WC, cc = p - r * WC;
            int y = min(max(ylo + r, 0), 63);
            int x = min(max(cxlo + cc, 0), 63);
            *(u16x8*)(win + p * WS + j * 8) =
                *(const u16x8*)(xb + (((y << 6) + x) << 6) + j * 8);
        }
    }
    __syncthreads();

    int pw  = w0 + l16;
    int ch0 = half * 32 + (quad << 3);   // this wave's channel half
    const float* o1p = off1 + (b * 18) * 4096 + (h << 6) + pw;
    const float* m1p = msk1 + (b * 9)  * 4096 + (h << 6) + pw;
    const float* o2p = off2 + (b * 50) * 4096 + (h << 6) + pw;
    const float* m2p = msk2 + (b * 25) * 4096 + (h << 6) + pw;
    const float* o3p = off3 + (b * 98) * 4096 + (h << 6) + pw;
    const float* m3p = msk3 + (b * 49) * 4096 + (h << 6) + pw;

    f32x4 acc[4];
    #pragma unroll
    for (int i = 0; i < 4; ++i) acc[i] = (f32x4){0.f, 0.f, 0.f, 0.f};

    // 8 single-range chunks: br1: 9 | br2: 12+13 | br3: 10/10/10/10/9
    switch (chunk) {
        case 0:  run_range<3,1,0,9>  (o1p, m1p, wp1, win, xb, h, pw, ylo, cxlo, ch0, l16, acc); break;
        case 1:  run_range<5,2,0,12> (o2p, m2p, wp2, win, xb, h, pw, ylo, cxlo, ch0, l16, acc); break;
        case 2:  run_range<5,2,12,25>(o2p, m2p, wp2, win, xb, h, pw, ylo, cxlo, ch0, l16, acc); break;
        case 3:  run_range<7,3,0,10> (o3p, m3p, wp3, win, xb, h, pw, ylo, cxlo, ch0, l16, acc); break;
        case 4:  run_range<7,3,10,20>(o3p, m3p, wp3, win, xb, h, pw, ylo, cxlo, ch0, l16, acc); break;
        case 5:  run_range<7,3,20,30>(o3p, m3p, wp3, win, xb, h, pw, ylo, cxlo, ch0, l16, acc); break;
        case 6:  run_range<7,3,30,40>(o3p, m3p, wp3, win, xb, h, pw, ylo, cxlo, ch0, l16, acc); break;
        default: run_range<7,3,40,49>(o3p, m3p, wp3, win, xb, h, pw, ylo, cxlo, ch0, l16, acc); break;
    }

    __syncthreads();    // all window reads done; safe to alias as slabs

    // phase A: half-0 waves write their slab
    if (half == 0) {
        #pragma unroll
        for (int ct = 0; ct < 4; ++ct) {
            *(f32x4*)&slab[chunk * 1280 + (ct * 16 + l16) * SLS + quad * 4] = acc[ct];
        }
    }
    __syncthreads();
    // phase B: half-1 waves add theirs
    if (half == 1) {
        #pragma unroll
        for (int ct = 0; ct < 4; ++ct) {
            float* p = &slab[chunk * 1280 + (ct * 16 + l16) * SLS + quad * 4];
            f32x4 old = *(f32x4*)p;
            #pragma unroll
            for (int r = 0; r < 4; ++r) old[r] += acc[ct][r];
            *(f32x4*)p = old;
        }
    }
    __syncthreads();

    // final reduce + store: 768 items = 192 o x 4 groups of 4 px
    // br0 (o<64): slab 0; br1: slabs 1+2; br2: slabs 3..7
    if (tid < 768) {
        int g = tid & 3;
        int o = tid >> 2;            // 0..191 (concat order br0|br1|br2)
        int oo = o & 63;
        int base = oo * SLS + g * 4;
        f32x4 v;
        if (o < 64) {
            v = *(const f32x4*)&slab[base];
        } else if (o < 128) {
            f32x4 a0 = *(const f32x4*)&slab[1 * 1280 + base];
            f32x4 a1 = *(const f32x4*)&slab[2 * 1280 + base];
            #pragma unroll
            for (int r = 0; r < 4; ++r) v[r] = a0[r] + a1[r];
        } else {
            f32x4 a0 = *(const f32x4*)&slab[3 * 1280 + base];
            f32x4 a1 = *(const f32x4*)&slab[4 * 1280 + base];
            f32x4 a2 = *(const f32x4*)&slab[5 * 1280 + base];
            f32x4 a3 = *(const f32x4*)&slab[6 * 1280 + base];
            f32x4 a4 = *(const f32x4*)&slab[7 * 1280 + base];
            #pragma unroll
            for (int r = 0; r < 4; ++r) v[r] = (a0[r] + a1[r]) + (a2[r] + a3[r]) + a4[r];
        }
        *(f32x4*)&out[(((size_t)b * 192 + o) * 64 + h) * 64 + w0 + g * 4] = v;
    }
}

extern "C" void kernel_launch(void* const* d_in, const int* in_sizes, int n_in,
                              void* d_out, int out_size, void* d_ws, size_t ws_size,
                              hipStream_t stream) {
    const float* x    = (const float*)d_in[0];
    const float* f1   = (const float*)d_in[1];
    const float* off1 = (const float*)d_in[2];
    const float* msk1 = (const float*)d_in[3];
    const float* f2   = (const float*)d_in[4];
    const float* off2 = (const float*)d_in[5];
    const float* msk2 = (const float*)d_in[6];
    const float* f3   = (const float*)d_in[7];
    const float* off3 = (const float*)d_in[8];
    const float* msk3 = (const float*)d_in[9];
    float* out = (float*)d_out;

    // ws: xTb 2MB bf16 | wp1/wp2/wp3 bf16
    unsigned short* xTb = (unsigned short*)d_ws;
    unsigned short* wp1 = xTb + 4 * 64 * 64 * 64;
    unsigned short* wp2 = wp1 + 9 * 4096;
    unsigned short* wp3 = wp2 + 25 * 4096;

    k_prep<<<dim3(1584), dim3(256), 0, stream>>>(x, f1, f2, f3, xTb, wp1, wp2, wp3);
    k_dcn<<<dim3(1024), dim3(1024), 0, stream>>>(xTb,
                                                 off1, msk1, wp1,
                                                 off2, msk2, wp2,
                                                 off3, msk3, wp3,
                                                 out);
}

// Round 11
// 169.315 us; speedup vs baseline: 1.3745x; 1.1603x over previous
//
#include <hip/hip_runtime.h>
#include <hip/hip_bf16.h>

// DCNv2 inception, R11: fragment-major weights (coalesced B-frag loads).
// R10 proved occupancy is NOT the limiter (85% occ, slower). R8 base kept.
// Remaining divergent vmem: B-frag loads strided 128B/lane = 16-line
// gathers x8 per tap. Fix: prep writes wpF[k][ct][cg][lane][8] so each
// B-frag load is base + lane*16B -> one coalesced 1KB request. Everything
// else identical to R8 (95us): LDS window, 8 waves/512-block, batch param
// prefetch, rare-oow global fallback, in-block LDS reduce.

typedef __attribute__((ext_vector_type(8))) short bf16x8;
typedef __attribute__((ext_vector_type(8))) unsigned short u16x8;
typedef __attribute__((ext_vector_type(4))) float f32x4;
typedef __attribute__((ext_vector_type(2))) float f32x2;

#define WR 16    // window rows
#define WC 30    // window cols
#define WS 68    // window position stride in shorts (34 dwords -> +2 bank rotate)
#define SLS 20   // slab o-stride in floats

__device__ __forceinline__ unsigned short f2bf(float f) {
    __hip_bfloat16 h = __float2bfloat16(f);
    return *reinterpret_cast<unsigned short*>(&h);
}
__device__ __forceinline__ f32x2 unpk(unsigned u) {
    f32x2 r;
    r[0] = __uint_as_float(u << 16);
    r[1] = __uint_as_float(u & 0xffff0000u);
    return r;
}

// Merged prep: blocks [0,256): x[b][c][h][w] f32 -> xTb[b][h][w][c] bf16;
// blocks [256,1584): f[o][c][k] f32 -> wpF in MFMA-fragment order:
//   wpF[k][ct][cg][lane][j]  (lane=quad*16+l16)  =
//   f[o=ct*16+(lane&15)][c=cg*32+(lane>>4)*8+j][k]
__global__ __launch_bounds__(256) void k_prep(
    const float* __restrict__ x,
    const float* __restrict__ f1, const float* __restrict__ f2, const float* __restrict__ f3,
    unsigned short* __restrict__ xTb,
    unsigned short* __restrict__ wp1, unsigned short* __restrict__ wp2, unsigned short* __restrict__ wp3) {
    __shared__ float tile[64][65];
    int bid = blockIdx.x;
    int tid = threadIdx.x;
    if (bid < 256) {
        int b = bid >> 6, h = bid & 63;
        {
            int w = tid & 63, c4 = tid >> 6;
            const float* xp = x + (((b * 64) * 64 + h) * 64) + w;
            #pragma unroll
            for (int i = 0; i < 16; ++i) {
                int c = c4 * 16 + i;
                tile[c][w] = xp[c * 4096];
            }
        }
        __syncthreads();
        {
            int c = tid & 63, w4 = tid >> 6;
            unsigned short* op = xTb + (((b * 64 + h) * 64) * 64) + c;
            #pragma unroll
            for (int i = 0; i < 16; ++i) {
                int ww = w4 * 16 + i;
                op[ww * 64] = f2bf(tile[c][ww]);
            }
        }
    } else {
        int idx = (bid - 256) * 256 + tid;      // 83*4096 = 339968 total
        const float* f; unsigned short* wp; int K, rel;
        if (idx < 36864)       { f = f1; wp = wp1; K = 9;  rel = idx; }
        else if (idx < 139264) { f = f2; wp = wp2; K = 25; rel = idx - 36864; }
        else                   { f = f3; wp = wp3; K = 49; rel = idx - 139264; }
        int k    = rel >> 12;
        int r2   = rel & 4095;
        int ct   = r2 >> 10;
        int cg   = (r2 >> 9) & 1;
        int lane = (r2 >> 3) & 63;
        int j    = r2 & 7;
        int o = ct * 16 + (lane & 15);
        int c = cg * 32 + (lane >> 4) * 8 + j;
        wp[rel] = f2bf(f[(o * 64 + c) * K + k]);
    }
}

// One tap-range of one branch, accumulating 16px x 64o into acc[4].
// lofs = lane*8 (shorts) for fragment-major B loads.
template<int KW, int PAD, int KS, int KE>
__device__ __forceinline__ void run_range(
    const float* __restrict__ offp, const float* __restrict__ mskp,
    const unsigned short* __restrict__ wpF, const unsigned short* __restrict__ win,
    const unsigned short* __restrict__ xb,
    int h, int pw, int ylo, int cxlo, int ch0, int lofs, f32x4 acc[4]) {

    constexpr int NT = KE - KS;

    // ---- batch prefetch: all taps' params at once (one HBM latency) ----
    float dys[NT], dxs[NT], mks[NT];
    #pragma unroll
    for (int i = 0; i < NT; ++i) {
        dys[i] = offp[(KS + i) * 8192];
        dxs[i] = offp[(KS + i) * 8192 + 4096];
        mks[i] = mskp[(KS + i) * 4096];
    }

    #pragma unroll
    for (int i = 0; i < NT; ++i) {
        const int k = KS + i;
        const int ky = k / KW, kx = k - ky * KW;
        float dy = dys[i];
        float dx = dxs[i];
        float mk = mks[i];
        float py = (float)(h - PAD + ky) + dy;
        float px = (float)(pw - PAD + kx) + dx;
        float y0f = floorf(py), x0f = floorf(px);
        float wy = py - y0f, wx = px - x0f;
        int y0 = (int)y0f, x0 = (int)x0f;
        int y1 = y0 + 1, x1 = x0 + 1;
        float fy0 = ((unsigned)y0 < 64u) ? (1.f - wy) * mk : 0.f;
        float fy1 = ((unsigned)y1 < 64u) ? wy * mk         : 0.f;
        float gx0 = ((unsigned)x0 < 64u) ? (1.f - wx)      : 0.f;
        float gx1 = ((unsigned)x1 < 64u) ? wx              : 0.f;
        float w00 = fy0 * gx0, w01 = fy0 * gx1, w10 = fy1 * gx0, w11 = fy1 * gx1;

        int r0 = y0 - ylo, r1 = r0 + 1;
        int c0 = x0 - cxlo, c1 = c0 + 1;
        bool oow = ((w00 != 0.f) & (((unsigned)r0 >= WR) | ((unsigned)c0 >= WC)))
                 | ((w01 != 0.f) & (((unsigned)r0 >= WR) | ((unsigned)c1 >= WC)))
                 | ((w10 != 0.f) & (((unsigned)r1 >= WR) | ((unsigned)c0 >= WC)))
                 | ((w11 != 0.f) & (((unsigned)r1 >= WR) | ((unsigned)c1 >= WC)));
        int r0c = min(max(r0, 0), WR - 1), r1c = min(max(r1, 0), WR - 1);
        int c0c = min(max(c0, 0), WC - 1), c1c = min(max(c1, 0), WC - 1);
        int p00 = (r0c * WC + c0c) * WS;
        int p01 = (r0c * WC + c1c) * WS;
        int p10 = (r1c * WC + c0c) * WS;
        int p11 = (r1c * WC + c1c) * WS;

        union U { u16x8 v; unsigned u[4]; };
        U g00a, g01a, g10a, g11a, g00b, g01b, g10b, g11b;
        g00a.v = *(const u16x8*)(win + p00 + ch0);
        g01a.v = *(const u16x8*)(win + p01 + ch0);
        g10a.v = *(const u16x8*)(win + p10 + ch0);
        g11a.v = *(const u16x8*)(win + p11 + ch0);
        g00b.v = *(const u16x8*)(win + p00 + 32 + ch0);
        g01b.v = *(const u16x8*)(win + p01 + 32 + ch0);
        g10b.v = *(const u16x8*)(win + p10 + 32 + ch0);
        g11b.v = *(const u16x8*)(win + p11 + 32 + ch0);

        if (oow) {   // valid corner outside window: needs |off|>~4sd, ~never
            int y0g = min(max(y0, 0), 63), y1g = min(max(y1, 0), 63);
            int x0g = min(max(x0, 0), 63), x1g = min(max(x1, 0), 63);
            int o00 = ((y0g << 6) + x0g) << 6;
            int o01 = ((y0g << 6) + x1g) << 6;
            int o10 = ((y1g << 6) + x0g) << 6;
            int o11 = ((y1g << 6) + x1g) << 6;
            g00a.v = *(const u16x8*)(xb + o00 + ch0);
            g01a.v = *(const u16x8*)(xb + o01 + ch0);
            g10a.v = *(const u16x8*)(xb + o10 + ch0);
            g11a.v = *(const u16x8*)(xb + o11 + ch0);
            g00b.v = *(const u16x8*)(xb + o00 + 32 + ch0);
            g01b.v = *(const u16x8*)(xb + o01 + 32 + ch0);
            g10b.v = *(const u16x8*)(xb + o10 + 32 + ch0);
            g11b.v = *(const u16x8*)(xb + o11 + 32 + ch0);
        }

        f32x2 W00 = {w00, w00}, W01 = {w01, w01}, W10 = {w10, w10}, W11 = {w11, w11};
        union { bf16x8 v; unsigned short u[8]; } A0, A1;
        #pragma unroll
        for (int j2 = 0; j2 < 4; ++j2) {
            f32x2 s0 = W00 * unpk(g00a.u[j2]) + W01 * unpk(g01a.u[j2])
                     + W10 * unpk(g10a.u[j2]) + W11 * unpk(g11a.u[j2]);
            f32x2 s1 = W00 * unpk(g00b.u[j2]) + W01 * unpk(g01b.u[j2])
                     + W10 * unpk(g10b.u[j2]) + W11 * unpk(g11b.u[j2]);
            A0.u[2 * j2]     = f2bf(s0[0]);
            A0.u[2 * j2 + 1] = f2bf(s0[1]);
            A1.u[2 * j2]     = f2bf(s1[0]);
            A1.u[2 * j2 + 1] = f2bf(s1[1]);
        }

        // ---- coalesced fragment-major B loads: base + lane*16B ----
        const unsigned short* wpk = wpF + (k << 12) + lofs;
        #pragma unroll
        for (int ct = 0; ct < 4; ++ct) {
            bf16x8 b0 = *(const bf16x8*)(wpk + ct * 1024);
            bf16x8 b1 = *(const bf16x8*)(wpk + ct * 1024 + 512);
            acc[ct] = __builtin_amdgcn_mfma_f32_16x16x32_bf16(A0.v, b0, acc[ct], 0, 0, 0);
            acc[ct] = __builtin_amdgcn_mfma_f32_16x16x32_bf16(A1.v, b1, acc[ct], 0, 0, 0);
        }
    }
}

__global__ __launch_bounds__(512, 4) void k_dcn(
    const unsigned short* __restrict__ xTb,
    const float* __restrict__ off1, const float* __restrict__ msk1, const unsigned short* __restrict__ wp1,
    const float* __restrict__ off2, const float* __restrict__ msk2, const unsigned short* __restrict__ wp2,
    const float* __restrict__ off3, const float* __restrict__ msk3, const unsigned short* __restrict__ wp3,
    float* __restrict__ out) {

    __shared__ __align__(16) unsigned char smem[WR * WC * WS * 2];   // 65,280 B
    unsigned short* win = (unsigned short*)smem;
    float* slab = (float*)smem;          // aliased after taps complete (9*1280*4 = 46,080 B)

    int tile = blockIdx.x;               // 0..1023
    int b  = tile >> 8;
    int h  = (tile >> 2) & 63;
    int w0 = (tile & 3) << 4;

    int tid  = threadIdx.x;
    int wv   = tid >> 6;                 // 0..7
    int lane = tid & 63;
    int quad = lane >> 4;
    int l16  = lane & 15;
    int ylo  = h - 7, cxlo = w0 - 7;

    const unsigned short* xb = xTb + ((size_t)b << 18);

    // ---- stage window: 480 positions x 128 B, coalesced, 512 threads ----
    {
        int j = tid & 7;
        for (int p = tid >> 3; p < WR * WC; p += 64) {
            int r = p / WC, cc = p - r * WC;
            int y = min(max(ylo + r, 0), 63);
            int x = min(max(cxlo + cc, 0), 63);
            *(u16x8*)(win + p * WS + j * 8) =
                *(const u16x8*)(xb + (((y << 6) + x) << 6) + j * 8);
        }
    }
    __syncthreads();

    int pw   = w0 + l16;
    int ch0  = quad << 3;
    int lofs = lane << 3;                // lane*8 shorts = lane*16 B
    const float* o1p = off1 + (b * 18) * 4096 + (h << 6) + pw;
    const float* m1p = msk1 + (b * 9)  * 4096 + (h << 6) + pw;
    const float* o2p = off2 + (b * 50) * 4096 + (h << 6) + pw;
    const float* m2p = msk2 + (b * 25) * 4096 + (h << 6) + pw;
    const float* o3p = off3 + (b * 98) * 4096 + (h << 6) + pw;
    const float* m3p = msk3 + (b * 49) * 4096 + (h << 6) + pw;

    f32x4 accA[4], accB[4];
    #pragma unroll
    for (int i = 0; i < 4; ++i) { accA[i] = (f32x4){0,0,0,0}; accB[i] = (f32x4){0,0,0,0}; }
    int slabA, slabB = -1;

    // 8 balanced compile-time chunks over 83 taps: 9/11/11/(3+8)/10/10/10/11
    switch (wv) {
        case 0:
            run_range<3,1,0,9>  (o1p, m1p, wp1, win, xb, h, pw, ylo, cxlo, ch0, lofs, accA);
            slabA = 0; break;
        case 1:
            run_range<5,2,0,11> (o2p, m2p, wp2, win, xb, h, pw, ylo, cxlo, ch0, lofs, accA);
            slabA = 1; break;
        case 2:
            run_range<5,2,11,22>(o2p, m2p, wp2, win, xb, h, pw, ylo, cxlo, ch0, lofs, accA);
            slabA = 2; break;
        case 3:
            run_range<5,2,22,25>(o2p, m2p, wp2, win, xb, h, pw, ylo, cxlo, ch0, lofs, accA);
            slabA = 3;
            run_range<7,3,0,8>  (o3p, m3p, wp3, win, xb, h, pw, ylo, cxlo, ch0, lofs, accB);
            slabB = 4; break;
        case 4:
            run_range<7,3,8,18> (o3p, m3p, wp3, win, xb, h, pw, ylo, cxlo, ch0, lofs, accA);
            slabA = 5; break;
        case 5:
            run_range<7,3,18,28>(o3p, m3p, wp3, win, xb, h, pw, ylo, cxlo, ch0, lofs, accA);
            slabA = 6; break;
        case 6:
            run_range<7,3,28,38>(o3p, m3p, wp3, win, xb, h, pw, ylo, cxlo, ch0, lofs, accA);
            slabA = 7; break;
        default:
            run_range<7,3,38,49>(o3p, m3p, wp3, win, xb, h, pw, ylo, cxlo, ch0, lofs, accA);
            slabA = 8; break;
    }

    __syncthreads();    // all waves done reading window; safe to alias as slab

    #pragma unroll
    for (int ct = 0; ct < 4; ++ct) {
        *(f32x4*)&slab[slabA * 1280 + (ct * 16 + l16) * SLS + quad * 4] = accA[ct];
    }
    if (slabB >= 0) {
        #pragma unroll
        for (int ct = 0; ct < 4; ++ct) {
            *(f32x4*)&slab[slabB * 1280 + (ct * 16 + l16) * SLS + quad * 4] = accB[ct];
        }
    }
    __syncthreads();

    // in-block reduce + store: 768 items = 192 o x 4 groups of 4 px
    // br0 (o<64): slab 0; br1: slabs 1+2+3; br2: slabs 4..8
    for (int it = tid; it < 768; it += 512) {
        int g = it & 3;
        int o = it >> 2;            // 0..191 (concat order br0|br1|br2)
        int oo = o & 63;
        int base = oo * SLS + g * 4;
        f32x4 v;
        if (o < 64) {
            v = *(const f32x4*)&slab[base];
        } else if (o < 128) {
            f32x4 a0 = *(const f32x4*)&slab[1 * 1280 + base];
            f32x4 a1 = *(const f32x4*)&slab[2 * 1280 + base];
            f32x4 a2 = *(const f32x4*)&slab[3 * 1280 + base];
            #pragma unroll
            for (int r = 0; r < 4; ++r) v[r] = a0[r] + (a1[r] + a2[r]);
        } else {
            f32x4 a0 = *(const f32x4*)&slab[4 * 1280 + base];
            f32x4 a1 = *(const f32x4*)&slab[5 * 1280 + base];
            f32x4 a2 = *(const f32x4*)&slab[6 * 1280 + base];
            f32x4 a3 = *(const f32x4*)&slab[7 * 1280 + base];
            f32x4 a4 = *(const f32x4*)&slab[8 * 1280 + base];
            #pragma unroll
            for (int r = 0; r < 4; ++r) v[r] = (a0[r] + a1[r]) + (a2[r] + a3[r]) + a4[r];
        }
        *(f32x4*)&out[(((size_t)b * 192 + o) * 64 + h) * 64 + w0 + g * 4] = v;
    }
}

extern "C" void kernel_launch(void* const* d_in, const int* in_sizes, int n_in,
                              void* d_out, int out_size, void* d_ws, size_t ws_size,
                              hipStream_t stream) {
    const float* x    = (const float*)d_in[0];
    const float* f1   = (const float*)d_in[1];
    const float* off1 = (const float*)d_in[2];
    const float* msk1 = (const float*)d_in[3];
    const float* f2   = (const float*)d_in[4];
    const float* off2 = (const float*)d_in[5];
    const float* msk2 = (const float*)d_in[6];
    const float* f3   = (const float*)d_in[7];
    const float* off3 = (const float*)d_in[8];
    const float* msk3 = (const float*)d_in[9];
    float* out = (float*)d_out;

    // ws: xTb 2MB bf16 | wpF1/wpF2/wpF3 bf16 (fragment-major)
    unsigned short* xTb = (unsigned short*)d_ws;
    unsigned short* wp1 = xTb + 4 * 64 * 64 * 64;
    unsigned short* wp2 = wp1 + 9 * 4096;
    unsigned short* wp3 = wp2 + 25 * 4096;

    k_prep<<<dim3(1584), dim3(256), 0, stream>>>(x, f1, f2, f3, xTb, wp1, wp2, wp3);
    k_dcn<<<dim3(1024), dim3(512), 0, stream>>>(xTb,
                                                off1, msk1, wp1,
                                                off2, msk2, wp2,
                                                off3, msk3, wp3,
                                                out);
}

// Round 12
// 165.370 us; speedup vs baseline: 1.4073x; 1.0239x over previous
//
#include <hip/hip_runtime.h>
#include <hip/hip_bf16.h>

// DCNv2 inception, R12: compact shared-code tap loop (I-cache attack).
// R6-R11 invariant: all pipes <35% busy, ~2/3 of time unattributed stall,
// insensitive to occupancy/ILP/layout. Remaining suspect: instruction
// fetch -- 8 per-wave fully-unrolled template ranges = ~100KB live code
// per CU vs 32KB L1I. R12: ONE runtime-parameterized tap loop (~1.6KB)
// shared by all waves; per-wave descriptor via scalar switch; incremental
// ky/kx; params prefetched one tap ahead (ping-pong scalars). Body else
// identical to R11 (LDS window, oow fallback, fragment-major B, 8 MFMA).

typedef __attribute__((ext_vector_type(8))) short bf16x8;
typedef __attribute__((ext_vector_type(8))) unsigned short u16x8;
typedef __attribute__((ext_vector_type(4))) float f32x4;
typedef __attribute__((ext_vector_type(2))) float f32x2;

#define WR 16    // window rows
#define WC 30    // window cols
#define WS 68    // window position stride in shorts (34 dwords -> +2 bank rotate)
#define SLS 20   // slab o-stride in floats

__device__ __forceinline__ unsigned short f2bf(float f) {
    __hip_bfloat16 h = __float2bfloat16(f);
    return *reinterpret_cast<unsigned short*>(&h);
}
__device__ __forceinline__ f32x2 unpk(unsigned u) {
    f32x2 r;
    r[0] = __uint_as_float(u << 16);
    r[1] = __uint_as_float(u & 0xffff0000u);
    return r;
}

// Merged prep: blocks [0,256): x[b][c][h][w] f32 -> xTb[b][h][w][c] bf16;
// blocks [256,1584): f[o][c][k] f32 -> wpF in MFMA-fragment order:
//   wpF[k][ct][cg][lane][j] = f[o=ct*16+(lane&15)][c=cg*32+(lane>>4)*8+j][k]
__global__ __launch_bounds__(256) void k_prep(
    const float* __restrict__ x,
    const float* __restrict__ f1, const float* __restrict__ f2, const float* __restrict__ f3,
    unsigned short* __restrict__ xTb,
    unsigned short* __restrict__ wp1, unsigned short* __restrict__ wp2, unsigned short* __restrict__ wp3) {
    __shared__ float tile[64][65];
    int bid = blockIdx.x;
    int tid = threadIdx.x;
    if (bid < 256) {
        int b = bid >> 6, h = bid & 63;
        {
            int w = tid & 63, c4 = tid >> 6;
            const float* xp = x + (((b * 64) * 64 + h) * 64) + w;
            #pragma unroll
            for (int i = 0; i < 16; ++i) {
                int c = c4 * 16 + i;
                tile[c][w] = xp[c * 4096];
            }
        }
        __syncthreads();
        {
            int c = tid & 63, w4 = tid >> 6;
            unsigned short* op = xTb + (((b * 64 + h) * 64) * 64) + c;
            #pragma unroll
            for (int i = 0; i < 16; ++i) {
                int ww = w4 * 16 + i;
                op[ww * 64] = f2bf(tile[c][ww]);
            }
        }
    } else {
        int idx = (bid - 256) * 256 + tid;      // 83*4096 = 339968 total
        const float* f; unsigned short* wp; int K, rel;
        if (idx < 36864)       { f = f1; wp = wp1; K = 9;  rel = idx; }
        else if (idx < 139264) { f = f2; wp = wp2; K = 25; rel = idx - 36864; }
        else                   { f = f3; wp = wp3; K = 49; rel = idx - 139264; }
        int k    = rel >> 12;
        int r2   = rel & 4095;
        int ct   = r2 >> 10;
        int cg   = (r2 >> 9) & 1;
        int lane = (r2 >> 3) & 63;
        int j    = r2 & 7;
        int o = ct * 16 + (lane & 15);
        int c = cg * 32 + (lane >> 4) * 8 + j;
        wp[rel] = f2bf(f[(o * 64 + c) * K + k]);
    }
}

__global__ __launch_bounds__(512, 4) void k_dcn(
    const unsigned short* __restrict__ xTb,
    const float* __restrict__ off1, const float* __restrict__ msk1, const unsigned short* __restrict__ wp1,
    const float* __restrict__ off2, const float* __restrict__ msk2, const unsigned short* __restrict__ wp2,
    const float* __restrict__ off3, const float* __restrict__ msk3, const unsigned short* __restrict__ wp3,
    float* __restrict__ out) {

    __shared__ __align__(16) unsigned char smem[WR * WC * WS * 2];   // 65,280 B
    unsigned short* win = (unsigned short*)smem;
    float* slab = (float*)smem;          // aliased after taps (8*1280*4 = 40,960 B)

    int tile = blockIdx.x;               // 0..1023
    int b  = tile >> 8;
    int h  = (tile >> 2) & 63;
    int w0 = (tile & 3) << 4;

    int tid  = threadIdx.x;
    int wv   = tid >> 6;                 // 0..7
    int lane = tid & 63;
    int quad = lane >> 4;
    int l16  = lane & 15;
    int ylo  = h - 7, cxlo = w0 - 7;

    const unsigned short* xb = xTb + ((size_t)b << 18);

    // ---- stage window: 480 positions x 128 B, coalesced, 512 threads ----
    {
        int j = tid & 7;
        for (int p = tid >> 3; p < WR * WC; p += 64) {
            int r = p / WC, cc = p - r * WC;
            int y = min(max(ylo + r, 0), 63);
            int x = min(max(cxlo + cc, 0), 63);
            *(u16x8*)(win + p * WS + j * 8) =
                *(const u16x8*)(xb + (((y << 6) + x) << 6) + j * 8);
        }
    }
    __syncthreads();

    int pw   = w0 + l16;
    int ch0  = quad << 3;
    int lofs = lane << 3;                // lane*8 shorts = lane*16 B

    // ---- per-wave descriptor (scalar, compact): 8 single tap-ranges ----
    // wv0: br0 k0..9 | wv1: br1 0..12 | wv2: br1 12..25 | wv3..7: br2 in 10s
    const float* offs; const float* msks; const unsigned short* wpF;
    int ks, ke, kw, pad;
    switch (wv) {
        case 0:  offs = off1; msks = msk1; wpF = wp1; kw = 3; pad = 1; ks = 0;  ke = 9;  break;
        case 1:  offs = off2; msks = msk2; wpF = wp2; kw = 5; pad = 2; ks = 0;  ke = 12; break;
        case 2:  offs = off2; msks = msk2; wpF = wp2; kw = 5; pad = 2; ks = 12; ke = 25; break;
        case 3:  offs = off3; msks = msk3; wpF = wp3; kw = 7; pad = 3; ks = 0;  ke = 10; break;
        case 4:  offs = off3; msks = msk3; wpF = wp3; kw = 7; pad = 3; ks = 10; ke = 20; break;
        case 5:  offs = off3; msks = msk3; wpF = wp3; kw = 7; pad = 3; ks = 20; ke = 30; break;
        case 6:  offs = off3; msks = msk3; wpF = wp3; kw = 7; pad = 3; ks = 30; ke = 40; break;
        default: offs = off3; msks = msk3; wpF = wp3; kw = 7; pad = 3; ks = 40; ke = 49; break;
    }
    int K2 = (kw == 3) ? 9 : (kw == 5) ? 25 : 49;
    const float* offp = offs + ((b * 2 * K2) * 4096) + (h << 6) + pw;  // +k*8192 dy, +4096 dx
    const float* mskp = msks + ((b * K2) * 4096) + (h << 6) + pw;      // +k*4096

    f32x4 acc[4];
    #pragma unroll
    for (int i = 0; i < 4; ++i) acc[i] = (f32x4){0.f, 0.f, 0.f, 0.f};

    int ky = ks / kw, kx = ks - ky * kw;

    // ---- param software prefetch, one tap ahead (ping-pong scalars) ----
    float dyC = offp[ks * 8192];
    float dxC = offp[ks * 8192 + 4096];
    float mkC = mskp[ks * 4096];

    for (int k = ks; k < ke; ++k) {
        int kn = min(k + 1, ke - 1);
        float dyN = offp[kn * 8192];
        float dxN = offp[kn * 8192 + 4096];
        float mkN = mskp[kn * 4096];

        float py = (float)(h - pad + ky) + dyC;
        float px = (float)(pw - pad + kx) + dxC;
        float y0f = floorf(py), x0f = floorf(px);
        float wy = py - y0f, wx = px - x0f;
        int y0 = (int)y0f, x0 = (int)x0f;
        int y1 = y0 + 1, x1 = x0 + 1;
        float fy0 = ((unsigned)y0 < 64u) ? (1.f - wy) * mkC : 0.f;
        float fy1 = ((unsigned)y1 < 64u) ? wy * mkC         : 0.f;
        float gx0 = ((unsigned)x0 < 64u) ? (1.f - wx)       : 0.f;
        float gx1 = ((unsigned)x1 < 64u) ? wx               : 0.f;
        float w00 = fy0 * gx0, w01 = fy0 * gx1, w10 = fy1 * gx0, w11 = fy1 * gx1;

        int r0 = y0 - ylo, r1 = r0 + 1;
        int c0 = x0 - cxlo, c1 = c0 + 1;
        bool oow = ((w00 != 0.f) & (((unsigned)r0 >= WR) | ((unsigned)c0 >= WC)))
                 | ((w01 != 0.f) & (((unsigned)r0 >= WR) | ((unsigned)c1 >= WC)))
                 | ((w10 != 0.f) & (((unsigned)r1 >= WR) | ((unsigned)c0 >= WC)))
                 | ((w11 != 0.f) & (((unsigned)r1 >= WR) | ((unsigned)c1 >= WC)));
        int r0c = min(max(r0, 0), WR - 1), r1c = min(max(r1, 0), WR - 1);
        int c0c = min(max(c0, 0), WC - 1), c1c = min(max(c1, 0), WC - 1);
        int p00 = (r0c * WC + c0c) * WS;
        int p01 = (r0c * WC + c1c) * WS;
        int p10 = (r1c * WC + c0c) * WS;
        int p11 = (r1c * WC + c1c) * WS;

        union U { u16x8 v; unsigned u[4]; };
        U g00a, g01a, g10a, g11a, g00b, g01b, g10b, g11b;
        g00a.v = *(const u16x8*)(win + p00 + ch0);
        g01a.v = *(const u16x8*)(win + p01 + ch0);
        g10a.v = *(const u16x8*)(win + p10 + ch0);
        g11a.v = *(const u16x8*)(win + p11 + ch0);
        g00b.v = *(const u16x8*)(win + p00 + 32 + ch0);
        g01b.v = *(const u16x8*)(win + p01 + 32 + ch0);
        g10b.v = *(const u16x8*)(win + p10 + 32 + ch0);
        g11b.v = *(const u16x8*)(win + p11 + 32 + ch0);

        if (oow) {   // valid corner outside window: needs |off|>~4sd, ~never
            int y0g = min(max(y0, 0), 63), y1g = min(max(y1, 0), 63);
            int x0g = min(max(x0, 0), 63), x1g = min(max(x1, 0), 63);
            int o00 = ((y0g << 6) + x0g) << 6;
            int o01 = ((y0g << 6) + x1g) << 6;
            int o10 = ((y1g << 6) + x0g) << 6;
            int o11 = ((y1g << 6) + x1g) << 6;
            g00a.v = *(const u16x8*)(xb + o00 + ch0);
            g01a.v = *(const u16x8*)(xb + o01 + ch0);
            g10a.v = *(const u16x8*)(xb + o10 + ch0);
            g11a.v = *(const u16x8*)(xb + o11 + ch0);
            g00b.v = *(const u16x8*)(xb + o00 + 32 + ch0);
            g01b.v = *(const u16x8*)(xb + o01 + 32 + ch0);
            g10b.v = *(const u16x8*)(xb + o10 + 32 + ch0);
            g11b.v = *(const u16x8*)(xb + o11 + 32 + ch0);
        }

        f32x2 W00 = {w00, w00}, W01 = {w01, w01}, W10 = {w10, w10}, W11 = {w11, w11};
        union { bf16x8 v; unsigned short u[8]; } A0, A1;
        #pragma unroll
        for (int j2 = 0; j2 < 4; ++j2) {
            f32x2 s0 = W00 * unpk(g00a.u[j2]) + W01 * unpk(g01a.u[j2])
                     + W10 * unpk(g10a.u[j2]) + W11 * unpk(g11a.u[j2]);
            f32x2 s1 = W00 * unpk(g00b.u[j2]) + W01 * unpk(g01b.u[j2])
                     + W10 * unpk(g10b.u[j2]) + W11 * unpk(g11b.u[j2]);
            A0.u[2 * j2]     = f2bf(s0[0]);
            A0.u[2 * j2 + 1] = f2bf(s0[1]);
            A1.u[2 * j2]     = f2bf(s1[0]);
            A1.u[2 * j2 + 1] = f2bf(s1[1]);
        }

        const unsigned short* wpk = wpF + (k << 12) + lofs;
        #pragma unroll
        for (int ct = 0; ct < 4; ++ct) {
            bf16x8 b0 = *(const bf16x8*)(wpk + ct * 1024);
            bf16x8 b1 = *(const bf16x8*)(wpk + ct * 1024 + 512);
            acc[ct] = __builtin_amdgcn_mfma_f32_16x16x32_bf16(A0.v, b0, acc[ct], 0, 0, 0);
            acc[ct] = __builtin_amdgcn_mfma_f32_16x16x32_bf16(A1.v, b1, acc[ct], 0, 0, 0);
        }

        dyC = dyN; dxC = dxN; mkC = mkN;
        if (++kx == kw) { kx = 0; ++ky; }
    }

    __syncthreads();    // all waves done reading window; safe to alias as slab

    #pragma unroll
    for (int ct = 0; ct < 4; ++ct) {
        *(f32x4*)&slab[wv * 1280 + (ct * 16 + l16) * SLS + quad * 4] = acc[ct];
    }
    __syncthreads();

    // in-block reduce + store: 768 items = 192 o x 4 groups of 4 px
    // br0 (o<64): slab 0; br1: slabs 1+2; br2: slabs 3..7
    for (int it = tid; it < 768; it += 512) {
        int g = it & 3;
        int o = it >> 2;            // 0..191 (concat order br0|br1|br2)
        int oo = o & 63;
        int base = oo * SLS + g * 4;
        f32x4 v;
        if (o < 64) {
            v = *(const f32x4*)&slab[base];
        } else if (o < 128) {
            f32x4 a0 = *(const f32x4*)&slab[1 * 1280 + base];
            f32x4 a1 = *(const f32x4*)&slab[2 * 1280 + base];
            #pragma unroll
            for (int r = 0; r < 4; ++r) v[r] = a0[r] + a1[r];
        } else {
            f32x4 a0 = *(const f32x4*)&slab[3 * 1280 + base];
            f32x4 a1 = *(const f32x4*)&slab[4 * 1280 + base];
            f32x4 a2 = *(const f32x4*)&slab[5 * 1280 + base];
            f32x4 a3 = *(const f32x4*)&slab[6 * 1280 + base];
            f32x4 a4 = *(const f32x4*)&slab[7 * 1280 + base];
            #pragma unroll
            for (int r = 0; r < 4; ++r) v[r] = (a0[r] + a1[r]) + (a2[r] + a3[r]) + a4[r];
        }
        *(f32x4*)&out[(((size_t)b * 192 + o) * 64 + h) * 64 + w0 + g * 4] = v;
    }
}

extern "C" void kernel_launch(void* const* d_in, const int* in_sizes, int n_in,
                              void* d_out, int out_size, void* d_ws, size_t ws_size,
                              hipStream_t stream) {
    const float* x    = (const float*)d_in[0];
    const float* f1   = (const float*)d_in[1];
    const float* off1 = (const float*)d_in[2];
    const float* msk1 = (const float*)d_in[3];
    const float* f2   = (const float*)d_in[4];
    const float* off2 = (const float*)d_in[5];
    const float* msk2 = (const float*)d_in[6];
    const float* f3   = (const float*)d_in[7];
    const float* off3 = (const float*)d_in[8];
    const float* msk3 = (const float*)d_in[9];
    float* out = (float*)d_out;

    // ws: xTb 2MB bf16 | wpF1/wpF2/wpF3 bf16 (fragment-major)
    unsigned short* xTb = (unsigned short*)d_ws;
    unsigned short* wp1 = xTb + 4 * 64 * 64 * 64;
    unsigned short* wp2 = wp1 + 9 * 4096;
    unsigned short* wp3 = wp2 + 25 * 4096;

    k_prep<<<dim3(1584), dim3(256), 0, stream>>>(x, f1, f2, f3, xTb, wp1, wp2, wp3);
    k_dcn<<<dim3(1024), dim3(512), 0, stream>>>(xTb,
                                                off1, msk1, wp1,
                                                off2, msk2, wp2,
                                                off3, msk3, wp3,
                                                out);
}